// Round 9
// baseline (114.351 us; speedup 1.0000x reference)
//
#include <hip/hip_runtime.h>
#include <cstdint>

#define NCELLS (48*48*48)   // 110592
#define NT 48
#define CB 64               // cells per block in k_cell
#define NW 8                // waves per block; each wave does 6 tris
#define PITCH 97            // topo LDS row pitch (97 % 32 == 1 -> 2 lanes/bank = free)
#define OFFE 882            // staged off region: 3a * 2dx * 3dy * 49z floats

// ---------------- compile-time exact numpy RNG reproduction ----------------
namespace nprng {
typedef unsigned __int128 u128;
struct PCG { u128 state; u128 inc; int has32; uint32_t cached; };

constexpr u128 mult128() {
  return (((u128)2549297995355413924ULL) << 64) | (u128)4865540595714422341ULL;
}
constexpr void step(PCG& g) { g.state = g.state * mult128() + g.inc; }
constexpr uint64_t out64(const PCG& g) {
  uint64_t x = (uint64_t)(g.state >> 64) ^ (uint64_t)g.state;
  unsigned rot = (unsigned)(g.state >> 122);
  return (x >> rot) | (x << ((64u - rot) & 63u));
}
constexpr uint64_t next64(PCG& g) { step(g); return out64(g); }
constexpr uint32_t next32(PCG& g) {
  if (g.has32) { g.has32 = 0; return g.cached; }
  uint64_t v = next64(g);
  g.has32 = 1; g.cached = (uint32_t)(v >> 32);
  return (uint32_t)v;
}
constexpr uint32_t lemire32(PCG& g, uint32_t rngmax) {
  const uint32_t rng_excl = rngmax + 1u;
  uint64_t m = (uint64_t)next32(g) * (uint64_t)rng_excl;
  uint32_t leftover = (uint32_t)m;
  if (leftover < rng_excl) {
    const uint32_t threshold = (uint32_t)((0xFFFFFFFFu - rngmax) % rng_excl);
    while (leftover < threshold) {
      m = (uint64_t)next32(g) * (uint64_t)rng_excl;
      leftover = (uint32_t)m;
    }
  }
  return (uint32_t)(m >> 32);
}
constexpr uint64_t rbu(PCG& g, uint64_t rngmax) {
  if (rngmax == 0) return 0;
  return (uint64_t)lemire32(g, (uint32_t)rngmax);
}
constexpr uint32_t hashmix(uint32_t v, uint32_t& hc) {
  v ^= hc; hc *= 0x931e8875u; v *= hc; v ^= v >> 16; return v;
}
constexpr uint32_t mix2(uint32_t x, uint32_t y) {
  uint32_t r = 0xca01f9ddu * x - 0x4973f715u * y; r ^= r >> 16; return r;
}
constexpr PCG seed_pcg0() {
  PCG g{0, 0, 0, 0};
  uint32_t pool[4] = {};
  uint32_t hc = 0x43b0d7e5u;
  for (int i = 0; i < 4; i++) pool[i] = hashmix(0u, hc);
  for (int s = 0; s < 4; s++)
    for (int d = 0; d < 4; d++)
      if (s != d) pool[d] = mix2(pool[d], hashmix(pool[s], hc));
  uint32_t st[8] = {};
  uint32_t hb = 0x8b51f9ddu;
  for (int i = 0; i < 8; i++) {
    uint32_t v = pool[i & 3];
    v ^= hb; hb *= 0x58f38dedu; v *= hb; v ^= v >> 16;
    st[i] = v;
  }
  uint64_t w[4] = {};
  for (int i = 0; i < 4; i++) w[i] = (uint64_t)st[2 * i] | ((uint64_t)st[2 * i + 1] << 32);
  u128 initstate = (((u128)w[0]) << 64) | (u128)w[1];
  u128 initseq   = (((u128)w[2]) << 64) | (u128)w[3];
  g.state = 0; g.inc = (initseq << 1) | (u128)1;
  step(g); g.state += initstate; step(g);
  g.has32 = 0; g.cached = 0;
  return g;
}
constexpr void choice_nr(PCG& g, int pop, int n, int* outv, bool shuf) {
  uint64_t hs[64] = {};
  uint64_t set_size = (uint64_t)(1.2 * (double)n);
  uint64_t mask = set_size;
  mask |= mask >> 1; mask |= mask >> 2; mask |= mask >> 4;
  mask |= mask >> 8; mask |= mask >> 16; mask |= mask >> 32;
  for (int i = 0; i < 64; i++) hs[i] = ~0ULL;
  for (int j = pop - n; j < pop; j++) {
    uint64_t val = rbu(g, (uint64_t)j);
    uint64_t loc = val & mask;
    while (hs[loc] != ~0ULL && hs[loc] != val) loc = (loc + 1) & mask;
    if (hs[loc] == ~0ULL) { hs[loc] = val; outv[j - (pop - n)] = (int)val; }
    else {
      loc = (uint64_t)j & mask;
      while (hs[loc] != ~0ULL) loc = (loc + 1) & mask;
      hs[loc] = (uint64_t)j;
      outv[j - (pop - n)] = j;
    }
  }
  if (shuf) {
    for (int i = n - 1; i >= 1; i--) {
      uint64_t j = rbu(g, (uint64_t)i);
      int t = outv[i]; outv[i] = outv[(int)j]; outv[(int)j] = t;
    }
  }
}
} // namespace nprng

struct TriTab3 {
  float ub[NT][3];
  float wb[NT][3];
  int   a0[NT], a1[NT], a2[NT];
  int   lofc[NT][3];   // LDS off index const: ((a*2+cx)*3+cy)*49 + cz
  int   tto[NT];
};

constexpr TriTab3 make_tab() {
  TriTab3 T{};
  nprng::PCG g = nprng::seed_pcg0();
  int tri[NT][3] = {};
  for (int t = 0; t < NT; t++) nprng::choice_nr(g, 12, 3, tri[t], true);
  int tt[NT] = {};
  nprng::choice_nr(g, 96, NT, tt, true);
  for (int i = 1; i < NT; i++) {
    int v = tt[i], j = i - 1;
    while (j >= 0 && tt[j] > v) { tt[j + 1] = tt[j]; j--; }
    tt[j + 1] = v;
  }
  constexpr int EC[12][3] = {{0,0,0},{0,1,0},{0,0,1},{0,1,1},
                             {0,0,0},{1,0,0},{0,0,1},{1,0,1},
                             {0,0,0},{1,0,0},{0,1,0},{1,1,0}};
  constexpr int EA[12] = {0,0,0,0,1,1,1,1,2,2,2,2};
  for (int t = 0; t < NT; t++) {
    float B[3][3] = {};
    int ax[3] = {};
    for (int k = 0; k < 3; k++) {
      int e = tri[t][k];
      int a = EA[e];
      ax[k] = a;
      T.lofc[t][k] = ((a * 2 + EC[e][0]) * 3 + EC[e][1]) * 49 + EC[e][2];
      B[k][0] = (float)EC[e][0]; B[k][1] = (float)EC[e][1]; B[k][2] = (float)EC[e][2];
      B[k][a] += 0.5f;
    }
    for (int c = 0; c < 3; c++) {
      T.ub[t][c] = B[1][c] - B[0][c];
      T.wb[t][c] = B[2][c] - B[0][c];
    }
    T.a0[t] = ax[0]; T.a1[t] = ax[1]; T.a2[t] = ax[2];
    T.tto[t] = tt[t];
  }
  return T;
}

static constexpr TriTab3 TAB = make_tab();

// ---------------- kernels ----------------
template <int t>
__device__ __forceinline__ void do1(const float* __restrict__ loff, int lanebase,
                                    const float* __restrict__ myrow,
                                    float& s, float& mx, float& my, float& mz) {
  constexpr int L0 = TAB.lofc[t][0], L1 = TAB.lofc[t][1], L2 = TAB.lofc[t][2];
  constexpr int A0 = TAB.a0[t], A1 = TAB.a1[t], A2 = TAB.a2[t];
  float p  = myrow[TAB.tto[t]];
  float d0 = loff[lanebase + L0];
  float d1 = loff[lanebase + L1];
  float d2 = loff[lanebase + L2];
  float ux = TAB.ub[t][0] + (A1 == 0 ? d1 : 0.0f) - (A0 == 0 ? d0 : 0.0f);
  float uy = TAB.ub[t][1] + (A1 == 1 ? d1 : 0.0f) - (A0 == 1 ? d0 : 0.0f);
  float uz = TAB.ub[t][2] + (A1 == 2 ? d1 : 0.0f) - (A0 == 2 ? d0 : 0.0f);
  float wx = TAB.wb[t][0] + (A2 == 0 ? d2 : 0.0f) - (A0 == 0 ? d0 : 0.0f);
  float wy = TAB.wb[t][1] + (A2 == 1 ? d2 : 0.0f) - (A0 == 1 ? d0 : 0.0f);
  float wz = TAB.wb[t][2] + (A2 == 2 ? d2 : 0.0f) - (A0 == 2 ? d0 : 0.0f);
  float cxv = uy * wz - uz * wy;
  float cyv = uz * wx - ux * wz;
  float czv = ux * wy - uy * wx;
  float nn = cxv * cxv + cyv * cyv + czv * czv + 1e-8f;
  float rinv = rsqrtf(nn);
  s += p;
  float f = p * rinv;
  mx += f * cxv;
  my += f * cyv;
  mz += f * czv;
}

template <int T0>
__device__ __forceinline__ void do6(const float* __restrict__ loff, int lanebase,
                                    const float* __restrict__ myrow,
                                    float& s, float& mx, float& my, float& mz) {
  do1<T0 + 0>(loff, lanebase, myrow, s, mx, my, mz);
  do1<T0 + 1>(loff, lanebase, myrow, s, mx, my, mz);
  do1<T0 + 2>(loff, lanebase, myrow, s, mx, my, mz);
  do1<T0 + 3>(loff, lanebase, myrow, s, mx, my, mz);
  do1<T0 + 4>(loff, lanebase, myrow, s, mx, my, mz);
  do1<T0 + 5>(loff, lanebase, myrow, s, mx, my, mz);
}

// R7 structure exactly (best so far). Launched 3x as a DIAGNOSTIC to measure
// k_cell's duration in the timed window: launches 2 and 3 recompute identical
// ws4 values (idempotent), so (dur - 90.8)/2 = one warm k_cell.
__global__ __launch_bounds__(CB * NW) void k_cell(const float* __restrict__ off,
                                                  const float* __restrict__ topo,
                                                  float4* __restrict__ ws4,
                                                  float* __restrict__ out) {
  __shared__ float lds[CB * PITCH];
  __shared__ float loff[OFFE];
  __shared__ float4 red[CB * NW];
  const int tid = threadIdx.x;
  const int lane = tid & 63;
  const int cell0 = blockIdx.x * CB;

  if (blockIdx.x == 0 && tid == 0) *out = 0.0f;  // zero accumulator for k_pair

  // ---- stage off region: x fixed, y0..y0+2, z 0..48 -> 882 floats ----
  const int x0 = cell0 / 2304;
  const int y0 = (cell0 / 48) % 48;
  for (int e = tid; e < OFFE; e += CB * NW) {
    int r = e / 49, zz = e % 49;       // r = (a*2+dx)*3+dy
    int dy = r % 3, rr = r / 3;
    int dx = rr & 1, a = rr >> 1;
    loff[e] = off[a * 117649 + (x0 + dx) * 2401 + (y0 + dy) * 49 + zz];
  }

  // ---- coalesced topo staging: 64 rows x 24 float4 = 1536 float4, linear ----
  const float4* trow = (const float4*)(topo + (size_t)cell0 * 96);
#pragma unroll
  for (int it = 0; it < 3; ++it) {
    int ch = tid + CB * NW * it;
    float4 v = trow[ch];
    int r  = ch / 24;
    int c4 = (ch % 24) * 4;
    float* dst = &lds[r * PITCH + c4];
    dst[0] = v.x; dst[1] = v.y; dst[2] = v.z; dst[3] = v.w;
  }
  __syncthreads();

  // ---- per-(cell, sixth) compute ----
  const int cell = cell0 + lane;
  const int z = cell % 48;
  const int ly = ((cell / 48) % 48) - y0;        // 0 or 1 (no x-cross mid-block)
  const int lanebase = ly * 49 + z;
  const float* myrow = &lds[lane * PITCH];

  float s = 0.f, mx = 0.f, my = 0.f, mz = 0.f;
  const int wvu = __builtin_amdgcn_readfirstlane(tid >> 6);  // SGPR-uniform
  if (wvu == 0)      do6<0>(loff, lanebase, myrow, s, mx, my, mz);
  else if (wvu == 1) do6<6>(loff, lanebase, myrow, s, mx, my, mz);
  else if (wvu == 2) do6<12>(loff, lanebase, myrow, s, mx, my, mz);
  else if (wvu == 3) do6<18>(loff, lanebase, myrow, s, mx, my, mz);
  else if (wvu == 4) do6<24>(loff, lanebase, myrow, s, mx, my, mz);
  else if (wvu == 5) do6<30>(loff, lanebase, myrow, s, mx, my, mz);
  else if (wvu == 6) do6<36>(loff, lanebase, myrow, s, mx, my, mz);
  else               do6<42>(loff, lanebase, myrow, s, mx, my, mz);

  red[tid] = make_float4(s, mx, my, mz);
  __syncthreads();

  // ---- cross-wave combine: wave 0 sums the 8 eighths, writes float4 ----
  if (tid < 64) {
    float sx = 0.f, sy = 0.f, sz = 0.f, sw = 0.f;
#pragma unroll
    for (int w = 0; w < NW; w++) {
      float4 a = red[lane + 64 * w];
      sx += a.x; sy += a.y; sz += a.z; sw += a.w;
    }
    ws4[cell0 + lane] = make_float4(sx, sy, sz, sw);
  }
}

__global__ __launch_bounds__(256) void k_pair(const float4* __restrict__ ws4,
                                              float* __restrict__ out) {
  int cell = blockIdx.x * 256 + threadIdx.x;
  int z = cell % 48;
  int y = (cell / 48) % 48;
  int x = cell / 2304;
  float4 a = ws4[cell];
  float acc = a.x * a.x - (a.y * a.y + a.z * a.z + a.w * a.w);
  if (z < 47) {
    float4 b = ws4[cell + 1];
    acc += a.x * b.x - (a.y * b.y + a.z * b.z + a.w * b.w);
  }
  if (y < 47) {
    float4 b = ws4[cell + 48];
    acc += a.x * b.x - (a.y * b.y + a.z * b.z + a.w * b.w);
  }
  if (x < 47) {
    float4 b = ws4[cell + 2304];
    acc += a.x * b.x - (a.y * b.y + a.z * b.z + a.w * b.w);
  }
  acc *= 2.0f;
  for (int o = 32; o > 0; o >>= 1) acc += __shfl_down(acc, o, 64);
  __shared__ float lds[4];
  int lane = threadIdx.x & 63;
  int w = threadIdx.x >> 6;
  if (lane == 0) lds[w] = acc;
  __syncthreads();
  if (threadIdx.x == 0) atomicAdd(out, lds[0] + lds[1] + lds[2] + lds[3]);
}

extern "C" void kernel_launch(void* const* d_in, const int* in_sizes, int n_in,
                              void* d_out, int out_size, void* d_ws, size_t ws_size,
                              hipStream_t stream) {
  const float* off  = (const float*)d_in[0];   // [3,49,49,49] f32
  const float* topo = (const float*)d_in[1];   // [110592,96] f32
  float4* ws4 = (float4*)d_ws;                 // 110592 float4 = 1.77 MB
  float* out  = (float*)d_out;                 // scalar f32

  // DIAGNOSTIC: 3 identical k_cell launches (idempotent). (dur - R7dur)/2
  // measures one warm k_cell directly in the timed regime.
  k_cell<<<dim3(NCELLS / CB), dim3(CB * NW), 0, stream>>>(off, topo, ws4, out);
  k_cell<<<dim3(NCELLS / CB), dim3(CB * NW), 0, stream>>>(off, topo, ws4, out);
  k_cell<<<dim3(NCELLS / CB), dim3(CB * NW), 0, stream>>>(off, topo, ws4, out);
  k_pair<<<dim3(NCELLS / 256), dim3(256), 0, stream>>>(ws4, out);
}

// Round 10
// 93.578 us; speedup vs baseline: 1.2220x; 1.2220x over previous
//
#include <hip/hip_runtime.h>
#include <cstdint>

#define NCELLS (48*48*48)   // 110592
#define NT 48
#define CB 64               // cells per block
#define NTH 256             // threads (4 waves, do12 each)
#define WPITCH 49           // tbuf32 word pitch (49 % 32 odd -> conflict-free)
#define OFFE 882            // staged off region: 3a * 2dx * 3dy * 49z floats

// ---------------- compile-time exact numpy RNG reproduction ----------------
namespace nprng {
typedef unsigned __int128 u128;
struct PCG { u128 state; u128 inc; int has32; uint32_t cached; };

constexpr u128 mult128() {
  return (((u128)2549297995355413924ULL) << 64) | (u128)4865540595714422341ULL;
}
constexpr void step(PCG& g) { g.state = g.state * mult128() + g.inc; }
constexpr uint64_t out64(const PCG& g) {
  uint64_t x = (uint64_t)(g.state >> 64) ^ (uint64_t)g.state;
  unsigned rot = (unsigned)(g.state >> 122);
  return (x >> rot) | (x << ((64u - rot) & 63u));
}
constexpr uint64_t next64(PCG& g) { step(g); return out64(g); }
constexpr uint32_t next32(PCG& g) {
  if (g.has32) { g.has32 = 0; return g.cached; }
  uint64_t v = next64(g);
  g.has32 = 1; g.cached = (uint32_t)(v >> 32);
  return (uint32_t)v;
}
constexpr uint32_t lemire32(PCG& g, uint32_t rngmax) {
  const uint32_t rng_excl = rngmax + 1u;
  uint64_t m = (uint64_t)next32(g) * (uint64_t)rng_excl;
  uint32_t leftover = (uint32_t)m;
  if (leftover < rng_excl) {
    const uint32_t threshold = (uint32_t)((0xFFFFFFFFu - rngmax) % rng_excl);
    while (leftover < threshold) {
      m = (uint64_t)next32(g) * (uint64_t)rng_excl;
      leftover = (uint32_t)m;
    }
  }
  return (uint32_t)(m >> 32);
}
constexpr uint64_t rbu(PCG& g, uint64_t rngmax) {
  if (rngmax == 0) return 0;
  return (uint64_t)lemire32(g, (uint32_t)rngmax);
}
constexpr uint32_t hashmix(uint32_t v, uint32_t& hc) {
  v ^= hc; hc *= 0x931e8875u; v *= hc; v ^= v >> 16; return v;
}
constexpr uint32_t mix2(uint32_t x, uint32_t y) {
  uint32_t r = 0xca01f9ddu * x - 0x4973f715u * y; r ^= r >> 16; return r;
}
constexpr PCG seed_pcg0() {
  PCG g{0, 0, 0, 0};
  uint32_t pool[4] = {};
  uint32_t hc = 0x43b0d7e5u;
  for (int i = 0; i < 4; i++) pool[i] = hashmix(0u, hc);
  for (int s = 0; s < 4; s++)
    for (int d = 0; d < 4; d++)
      if (s != d) pool[d] = mix2(pool[d], hashmix(pool[s], hc));
  uint32_t st[8] = {};
  uint32_t hb = 0x8b51f9ddu;
  for (int i = 0; i < 8; i++) {
    uint32_t v = pool[i & 3];
    v ^= hb; hb *= 0x58f38dedu; v *= hb; v ^= v >> 16;
    st[i] = v;
  }
  uint64_t w[4] = {};
  for (int i = 0; i < 4; i++) w[i] = (uint64_t)st[2 * i] | ((uint64_t)st[2 * i + 1] << 32);
  u128 initstate = (((u128)w[0]) << 64) | (u128)w[1];
  u128 initseq   = (((u128)w[2]) << 64) | (u128)w[3];
  g.state = 0; g.inc = (initseq << 1) | (u128)1;
  step(g); g.state += initstate; step(g);
  g.has32 = 0; g.cached = 0;
  return g;
}
constexpr void choice_nr(PCG& g, int pop, int n, int* outv, bool shuf) {
  uint64_t hs[64] = {};
  uint64_t set_size = (uint64_t)(1.2 * (double)n);
  uint64_t mask = set_size;
  mask |= mask >> 1; mask |= mask >> 2; mask |= mask >> 4;
  mask |= mask >> 8; mask |= mask >> 16; mask |= mask >> 32;
  for (int i = 0; i < 64; i++) hs[i] = ~0ULL;
  for (int j = pop - n; j < pop; j++) {
    uint64_t val = rbu(g, (uint64_t)j);
    uint64_t loc = val & mask;
    while (hs[loc] != ~0ULL && hs[loc] != val) loc = (loc + 1) & mask;
    if (hs[loc] == ~0ULL) { hs[loc] = val; outv[j - (pop - n)] = (int)val; }
    else {
      loc = (uint64_t)j & mask;
      while (hs[loc] != ~0ULL) loc = (loc + 1) & mask;
      hs[loc] = (uint64_t)j;
      outv[j - (pop - n)] = j;
    }
  }
  if (shuf) {
    for (int i = n - 1; i >= 1; i--) {
      uint64_t j = rbu(g, (uint64_t)i);
      int t = outv[i]; outv[i] = outv[(int)j]; outv[(int)j] = t;
    }
  }
}
} // namespace nprng

struct TriTab3 {
  float ub[NT][3];
  float wb[NT][3];
  int   a0[NT], a1[NT], a2[NT];
  int   lofc[NT][3];   // LDS off index const: ((a*2+cx)*3+cy)*49 + cz
  int   tto[NT];
};

constexpr TriTab3 make_tab() {
  TriTab3 T{};
  nprng::PCG g = nprng::seed_pcg0();
  int tri[NT][3] = {};
  for (int t = 0; t < NT; t++) nprng::choice_nr(g, 12, 3, tri[t], true);
  int tt[NT] = {};
  nprng::choice_nr(g, 96, NT, tt, true);
  for (int i = 1; i < NT; i++) {
    int v = tt[i], j = i - 1;
    while (j >= 0 && tt[j] > v) { tt[j + 1] = tt[j]; j--; }
    tt[j + 1] = v;
  }
  constexpr int EC[12][3] = {{0,0,0},{0,1,0},{0,0,1},{0,1,1},
                             {0,0,0},{1,0,0},{0,0,1},{1,0,1},
                             {0,0,0},{1,0,0},{0,1,0},{1,1,0}};
  constexpr int EA[12] = {0,0,0,0,1,1,1,1,2,2,2,2};
  for (int t = 0; t < NT; t++) {
    float B[3][3] = {};
    int ax[3] = {};
    for (int k = 0; k < 3; k++) {
      int e = tri[t][k];
      int a = EA[e];
      ax[k] = a;
      T.lofc[t][k] = ((a * 2 + EC[e][0]) * 3 + EC[e][1]) * 49 + EC[e][2];
      B[k][0] = (float)EC[e][0]; B[k][1] = (float)EC[e][1]; B[k][2] = (float)EC[e][2];
      B[k][a] += 0.5f;
    }
    for (int c = 0; c < 3; c++) {
      T.ub[t][c] = B[1][c] - B[0][c];
      T.wb[t][c] = B[2][c] - B[0][c];
    }
    T.a0[t] = ax[0]; T.a1[t] = ax[1]; T.a2[t] = ax[2];
    T.tto[t] = tt[t];
  }
  return T;
}

static constexpr TriTab3 TAB = make_tab();

// ---------------- kernels ----------------
// f32 -> bf16 with round-to-nearest-even (bit trick, 3 VALU)
__device__ __forceinline__ uint32_t bfr(float f) {
  uint32_t u = __float_as_uint(f);
  return (u + 0x7FFFu + ((u >> 16) & 1u)) >> 16;
}

// One triangle: table values are immediates; p comes from the bf16 topo word
// buffer (word index tto>>1, half tto&1 both compile-time); d0/d1/d2 from the
// staged f32 off-region. All LDS, zero global traffic in compute.
template <int t>
__device__ __forceinline__ void do1(const float* __restrict__ loff, int lanebase,
                                    const uint32_t* __restrict__ myrow,
                                    float& s, float& mx, float& my, float& mz) {
  constexpr int L0 = TAB.lofc[t][0], L1 = TAB.lofc[t][1], L2 = TAB.lofc[t][2];
  constexpr int A0 = TAB.a0[t], A1 = TAB.a1[t], A2 = TAB.a2[t];
  constexpr int W = TAB.tto[t] >> 1, H = TAB.tto[t] & 1;
  uint32_t pw = myrow[W];
  float p = __uint_as_float(H ? (pw & 0xFFFF0000u) : (pw << 16));
  float d0 = loff[lanebase + L0];
  float d1 = loff[lanebase + L1];
  float d2 = loff[lanebase + L2];
  float ux = TAB.ub[t][0] + (A1 == 0 ? d1 : 0.0f) - (A0 == 0 ? d0 : 0.0f);
  float uy = TAB.ub[t][1] + (A1 == 1 ? d1 : 0.0f) - (A0 == 1 ? d0 : 0.0f);
  float uz = TAB.ub[t][2] + (A1 == 2 ? d1 : 0.0f) - (A0 == 2 ? d0 : 0.0f);
  float wx = TAB.wb[t][0] + (A2 == 0 ? d2 : 0.0f) - (A0 == 0 ? d0 : 0.0f);
  float wy = TAB.wb[t][1] + (A2 == 1 ? d2 : 0.0f) - (A0 == 1 ? d0 : 0.0f);
  float wz = TAB.wb[t][2] + (A2 == 2 ? d2 : 0.0f) - (A0 == 2 ? d0 : 0.0f);
  float cxv = uy * wz - uz * wy;
  float cyv = uz * wx - ux * wz;
  float czv = ux * wy - uy * wx;
  float nn = cxv * cxv + cyv * cyv + czv * czv + 1e-8f;
  float rinv = rsqrtf(nn);
  s += p;
  float f = p * rinv;
  mx += f * cxv;
  my += f * cyv;
  mz += f * czv;
}

template <int T0>
__device__ __forceinline__ void do12(const float* __restrict__ loff, int lanebase,
                                     const uint32_t* __restrict__ myrow,
                                     float& s, float& mx, float& my, float& mz) {
  do1<T0 + 0>(loff, lanebase, myrow, s, mx, my, mz);
  do1<T0 + 1>(loff, lanebase, myrow, s, mx, my, mz);
  do1<T0 + 2>(loff, lanebase, myrow, s, mx, my, mz);
  do1<T0 + 3>(loff, lanebase, myrow, s, mx, my, mz);
  do1<T0 + 4>(loff, lanebase, myrow, s, mx, my, mz);
  do1<T0 + 5>(loff, lanebase, myrow, s, mx, my, mz);
  do1<T0 + 6>(loff, lanebase, myrow, s, mx, my, mz);
  do1<T0 + 7>(loff, lanebase, myrow, s, mx, my, mz);
  do1<T0 + 8>(loff, lanebase, myrow, s, mx, my, mz);
  do1<T0 + 9>(loff, lanebase, myrow, s, mx, my, mz);
  do1<T0 + 10>(loff, lanebase, myrow, s, mx, my, mz);
  do1<T0 + 11>(loff, lanebase, myrow, s, mx, my, mz);
}

// 1728 blocks x 256 threads (4 waves x do12). Topo staged as bf16 words:
// tbuf 12.5 KB + loff 3.5 KB + red 4 KB ~ 20.2 KB -> 7 blocks/CU resident
// (vs 6.75 avg per CU): the whole grid is essentially co-resident, so every
// block's staging latency overlaps six other blocks' compute. Half the waves
// of the 512-thread version -> half the per-wave fixed overhead.
__global__ __launch_bounds__(NTH, 6) void k_cell(const float* __restrict__ off,
                                                 const float* __restrict__ topo,
                                                 float4* __restrict__ ws4,
                                                 float* __restrict__ out) {
  __shared__ uint32_t tbuf32[CB * WPITCH];  // bf16 pairs, word pitch 49
  __shared__ float loff[OFFE];
  __shared__ float4 red[NTH];
  const int tid = threadIdx.x;
  const int lane = tid & 63;
  const int cell0 = blockIdx.x * CB;

  if (blockIdx.x == 0 && tid == 0) *out = 0.0f;  // zero accumulator for k_pair

  // ---- stage off region: x fixed, y0..y0+2, z 0..48 -> 882 floats ----
  const int x0 = cell0 / 2304;
  const int y0 = (cell0 / 48) % 48;
  for (int e = tid; e < OFFE; e += NTH) {
    int r = e / 49, zz = e % 49;       // r = (a*2+dx)*3+dy
    int dy = r % 3, rr = r / 3;
    int dx = rr & 1, a = rr >> 1;
    loff[e] = off[a * 117649 + (x0 + dx) * 2401 + (y0 + dy) * 49 + zz];
  }

  // ---- coalesced topo staging: 1536 float4, converted to bf16 pairs ----
  const float4* trow = (const float4*)(topo + (size_t)cell0 * 96);
#pragma unroll
  for (int it = 0; it < 6; ++it) {
    int ch = tid + NTH * it;
    float4 v = trow[ch];
    int r  = ch / 24;
    int w0 = (ch % 24) * 2;
    tbuf32[r * WPITCH + w0]     = bfr(v.x) | (bfr(v.y) << 16);
    tbuf32[r * WPITCH + w0 + 1] = bfr(v.z) | (bfr(v.w) << 16);
  }
  __syncthreads();

  // ---- per-(cell, quarter) compute ----
  const int cell = cell0 + lane;
  const int z = cell % 48;
  const int ly = ((cell / 48) % 48) - y0;        // 0 or 1
  const int lanebase = ly * 49 + z;
  const uint32_t* myrow = &tbuf32[lane * WPITCH];

  float s = 0.f, mx = 0.f, my = 0.f, mz = 0.f;
  const int wvu = __builtin_amdgcn_readfirstlane(tid >> 6);  // SGPR-uniform
  if (wvu == 0)      do12<0>(loff, lanebase, myrow, s, mx, my, mz);
  else if (wvu == 1) do12<12>(loff, lanebase, myrow, s, mx, my, mz);
  else if (wvu == 2) do12<24>(loff, lanebase, myrow, s, mx, my, mz);
  else               do12<36>(loff, lanebase, myrow, s, mx, my, mz);

  red[tid] = make_float4(s, mx, my, mz);
  __syncthreads();

  // ---- cross-wave combine: wave 0 sums the 4 quarters, writes float4 ----
  if (tid < 64) {
    float4 a = red[lane];
    float4 b = red[lane + 64];
    float4 c = red[lane + 128];
    float4 d = red[lane + 192];
    ws4[cell0 + lane] = make_float4(a.x + b.x + c.x + d.x,
                                    a.y + b.y + c.y + d.y,
                                    a.z + b.z + c.z + d.z,
                                    a.w + b.w + c.w + d.w);
  }
}

__global__ __launch_bounds__(256) void k_pair(const float4* __restrict__ ws4,
                                              float* __restrict__ out) {
  int cell = blockIdx.x * 256 + threadIdx.x;
  int z = cell % 48;
  int y = (cell / 48) % 48;
  int x = cell / 2304;
  float4 a = ws4[cell];
  float acc = a.x * a.x - (a.y * a.y + a.z * a.z + a.w * a.w);
  if (z < 47) {
    float4 b = ws4[cell + 1];
    acc += a.x * b.x - (a.y * b.y + a.z * b.z + a.w * b.w);
  }
  if (y < 47) {
    float4 b = ws4[cell + 48];
    acc += a.x * b.x - (a.y * b.y + a.z * b.z + a.w * b.w);
  }
  if (x < 47) {
    float4 b = ws4[cell + 2304];
    acc += a.x * b.x - (a.y * b.y + a.z * b.z + a.w * b.w);
  }
  acc *= 2.0f;
  for (int o = 32; o > 0; o >>= 1) acc += __shfl_down(acc, o, 64);
  __shared__ float lds[4];
  int lane = threadIdx.x & 63;
  int w = threadIdx.x >> 6;
  if (lane == 0) lds[w] = acc;
  __syncthreads();
  if (threadIdx.x == 0) atomicAdd(out, lds[0] + lds[1] + lds[2] + lds[3]);
}

extern "C" void kernel_launch(void* const* d_in, const int* in_sizes, int n_in,
                              void* d_out, int out_size, void* d_ws, size_t ws_size,
                              hipStream_t stream) {
  const float* off  = (const float*)d_in[0];   // [3,49,49,49] f32
  const float* topo = (const float*)d_in[1];   // [110592,96] f32
  float4* ws4 = (float4*)d_ws;                 // 110592 float4 = 1.77 MB
  float* out  = (float*)d_out;                 // scalar f32

  k_cell<<<dim3(NCELLS / CB), dim3(NTH), 0, stream>>>(off, topo, ws4, out);
  k_pair<<<dim3(NCELLS / 256), dim3(256), 0, stream>>>(ws4, out);
}

// Round 11
// 90.772 us; speedup vs baseline: 1.2598x; 1.0309x over previous
//
#include <hip/hip_runtime.h>
#include <cstdint>

#define NCELLS (48*48*48)   // 110592
#define NT 48
#define CB 64               // cells per block in k_cell
#define NW 8                // waves per block; each wave does 6 tris
#define PITCH 97            // topo LDS row pitch (97 % 32 == 1 -> 2 lanes/bank = free)
#define OFFE 882            // staged off region: 3a * 2dx * 3dy * 49z floats

// ---------------- compile-time exact numpy RNG reproduction ----------------
namespace nprng {
typedef unsigned __int128 u128;
struct PCG { u128 state; u128 inc; int has32; uint32_t cached; };

constexpr u128 mult128() {
  return (((u128)2549297995355413924ULL) << 64) | (u128)4865540595714422341ULL;
}
constexpr void step(PCG& g) { g.state = g.state * mult128() + g.inc; }
constexpr uint64_t out64(const PCG& g) {
  uint64_t x = (uint64_t)(g.state >> 64) ^ (uint64_t)g.state;
  unsigned rot = (unsigned)(g.state >> 122);
  return (x >> rot) | (x << ((64u - rot) & 63u));
}
constexpr uint64_t next64(PCG& g) { step(g); return out64(g); }
constexpr uint32_t next32(PCG& g) {
  if (g.has32) { g.has32 = 0; return g.cached; }
  uint64_t v = next64(g);
  g.has32 = 1; g.cached = (uint32_t)(v >> 32);
  return (uint32_t)v;
}
constexpr uint32_t lemire32(PCG& g, uint32_t rngmax) {
  const uint32_t rng_excl = rngmax + 1u;
  uint64_t m = (uint64_t)next32(g) * (uint64_t)rng_excl;
  uint32_t leftover = (uint32_t)m;
  if (leftover < rng_excl) {
    const uint32_t threshold = (uint32_t)((0xFFFFFFFFu - rngmax) % rng_excl);
    while (leftover < threshold) {
      m = (uint64_t)next32(g) * (uint64_t)rng_excl;
      leftover = (uint32_t)m;
    }
  }
  return (uint32_t)(m >> 32);
}
constexpr uint64_t rbu(PCG& g, uint64_t rngmax) {
  if (rngmax == 0) return 0;
  return (uint64_t)lemire32(g, (uint32_t)rngmax);
}
constexpr uint32_t hashmix(uint32_t v, uint32_t& hc) {
  v ^= hc; hc *= 0x931e8875u; v *= hc; v ^= v >> 16; return v;
}
constexpr uint32_t mix2(uint32_t x, uint32_t y) {
  uint32_t r = 0xca01f9ddu * x - 0x4973f715u * y; r ^= r >> 16; return r;
}
constexpr PCG seed_pcg0() {
  PCG g{0, 0, 0, 0};
  uint32_t pool[4] = {};
  uint32_t hc = 0x43b0d7e5u;
  for (int i = 0; i < 4; i++) pool[i] = hashmix(0u, hc);
  for (int s = 0; s < 4; s++)
    for (int d = 0; d < 4; d++)
      if (s != d) pool[d] = mix2(pool[d], hashmix(pool[s], hc));
  uint32_t st[8] = {};
  uint32_t hb = 0x8b51f9ddu;
  for (int i = 0; i < 8; i++) {
    uint32_t v = pool[i & 3];
    v ^= hb; hb *= 0x58f38dedu; v *= hb; v ^= v >> 16;
    st[i] = v;
  }
  uint64_t w[4] = {};
  for (int i = 0; i < 4; i++) w[i] = (uint64_t)st[2 * i] | ((uint64_t)st[2 * i + 1] << 32);
  u128 initstate = (((u128)w[0]) << 64) | (u128)w[1];
  u128 initseq   = (((u128)w[2]) << 64) | (u128)w[3];
  g.state = 0; g.inc = (initseq << 1) | (u128)1;
  step(g); g.state += initstate; step(g);
  g.has32 = 0; g.cached = 0;
  return g;
}
constexpr void choice_nr(PCG& g, int pop, int n, int* outv, bool shuf) {
  uint64_t hs[64] = {};
  uint64_t set_size = (uint64_t)(1.2 * (double)n);
  uint64_t mask = set_size;
  mask |= mask >> 1; mask |= mask >> 2; mask |= mask >> 4;
  mask |= mask >> 8; mask |= mask >> 16; mask |= mask >> 32;
  for (int i = 0; i < 64; i++) hs[i] = ~0ULL;
  for (int j = pop - n; j < pop; j++) {
    uint64_t val = rbu(g, (uint64_t)j);
    uint64_t loc = val & mask;
    while (hs[loc] != ~0ULL && hs[loc] != val) loc = (loc + 1) & mask;
    if (hs[loc] == ~0ULL) { hs[loc] = val; outv[j - (pop - n)] = (int)val; }
    else {
      loc = (uint64_t)j & mask;
      while (hs[loc] != ~0ULL) loc = (loc + 1) & mask;
      hs[loc] = (uint64_t)j;
      outv[j - (pop - n)] = j;
    }
  }
  if (shuf) {
    for (int i = n - 1; i >= 1; i--) {
      uint64_t j = rbu(g, (uint64_t)i);
      int t = outv[i]; outv[i] = outv[(int)j]; outv[(int)j] = t;
    }
  }
}
} // namespace nprng

struct TriTab3 {
  float ub[NT][3];
  float wb[NT][3];
  int   a0[NT], a1[NT], a2[NT];
  int   lofc[NT][3];   // LDS off index const: ((a*2+cx)*3+cy)*49 + cz
  int   tto[NT];
};

constexpr TriTab3 make_tab() {
  TriTab3 T{};
  nprng::PCG g = nprng::seed_pcg0();
  int tri[NT][3] = {};
  for (int t = 0; t < NT; t++) nprng::choice_nr(g, 12, 3, tri[t], true);
  int tt[NT] = {};
  nprng::choice_nr(g, 96, NT, tt, true);
  for (int i = 1; i < NT; i++) {
    int v = tt[i], j = i - 1;
    while (j >= 0 && tt[j] > v) { tt[j + 1] = tt[j]; j--; }
    tt[j + 1] = v;
  }
  constexpr int EC[12][3] = {{0,0,0},{0,1,0},{0,0,1},{0,1,1},
                             {0,0,0},{1,0,0},{0,0,1},{1,0,1},
                             {0,0,0},{1,0,0},{0,1,0},{1,1,0}};
  constexpr int EA[12] = {0,0,0,0,1,1,1,1,2,2,2,2};
  for (int t = 0; t < NT; t++) {
    float B[3][3] = {};
    int ax[3] = {};
    for (int k = 0; k < 3; k++) {
      int e = tri[t][k];
      int a = EA[e];
      ax[k] = a;
      T.lofc[t][k] = ((a * 2 + EC[e][0]) * 3 + EC[e][1]) * 49 + EC[e][2];
      B[k][0] = (float)EC[e][0]; B[k][1] = (float)EC[e][1]; B[k][2] = (float)EC[e][2];
      B[k][a] += 0.5f;
    }
    for (int c = 0; c < 3; c++) {
      T.ub[t][c] = B[1][c] - B[0][c];
      T.wb[t][c] = B[2][c] - B[0][c];
    }
    T.a0[t] = ax[0]; T.a1[t] = ax[1]; T.a2[t] = ax[2];
    T.tto[t] = tt[t];
  }
  return T;
}

static constexpr TriTab3 TAB = make_tab();

// ---------------- kernels ----------------
template <int t>
__device__ __forceinline__ void do1(const float* __restrict__ loff, int lanebase,
                                    const float* __restrict__ myrow,
                                    float& s, float& mx, float& my, float& mz) {
  constexpr int L0 = TAB.lofc[t][0], L1 = TAB.lofc[t][1], L2 = TAB.lofc[t][2];
  constexpr int A0 = TAB.a0[t], A1 = TAB.a1[t], A2 = TAB.a2[t];
  float p  = myrow[TAB.tto[t]];
  float d0 = loff[lanebase + L0];
  float d1 = loff[lanebase + L1];
  float d2 = loff[lanebase + L2];
  float ux = TAB.ub[t][0] + (A1 == 0 ? d1 : 0.0f) - (A0 == 0 ? d0 : 0.0f);
  float uy = TAB.ub[t][1] + (A1 == 1 ? d1 : 0.0f) - (A0 == 1 ? d0 : 0.0f);
  float uz = TAB.ub[t][2] + (A1 == 2 ? d1 : 0.0f) - (A0 == 2 ? d0 : 0.0f);
  float wx = TAB.wb[t][0] + (A2 == 0 ? d2 : 0.0f) - (A0 == 0 ? d0 : 0.0f);
  float wy = TAB.wb[t][1] + (A2 == 1 ? d2 : 0.0f) - (A0 == 1 ? d0 : 0.0f);
  float wz = TAB.wb[t][2] + (A2 == 2 ? d2 : 0.0f) - (A0 == 2 ? d0 : 0.0f);
  float cxv = uy * wz - uz * wy;
  float cyv = uz * wx - ux * wz;
  float czv = ux * wy - uy * wx;
  float nn = cxv * cxv + cyv * cyv + czv * czv + 1e-8f;
  float rinv = rsqrtf(nn);
  s += p;
  float f = p * rinv;
  mx += f * cxv;
  my += f * cyv;
  mz += f * czv;
}

template <int T0>
__device__ __forceinline__ void do6(const float* __restrict__ loff, int lanebase,
                                    const float* __restrict__ myrow,
                                    float& s, float& mx, float& my, float& mz) {
  do1<T0 + 0>(loff, lanebase, myrow, s, mx, my, mz);
  do1<T0 + 1>(loff, lanebase, myrow, s, mx, my, mz);
  do1<T0 + 2>(loff, lanebase, myrow, s, mx, my, mz);
  do1<T0 + 3>(loff, lanebase, myrow, s, mx, my, mz);
  do1<T0 + 4>(loff, lanebase, myrow, s, mx, my, mz);
  do1<T0 + 5>(loff, lanebase, myrow, s, mx, my, mz);
}

// FINAL: best-measured variant (R7, 90.81 µs). 64 cells/block, 512 threads
// (8 waves, 6 tris each, readfirstlane scalar dispatch, all table constants
// folded to immediates); topo + off both staged in LDS, zero per-lane global
// loads in compute.
__global__ __launch_bounds__(CB * NW) void k_cell(const float* __restrict__ off,
                                                  const float* __restrict__ topo,
                                                  float4* __restrict__ ws4,
                                                  float* __restrict__ out) {
  __shared__ float lds[CB * PITCH];
  __shared__ float loff[OFFE];
  __shared__ float4 red[CB * NW];
  const int tid = threadIdx.x;
  const int lane = tid & 63;
  const int cell0 = blockIdx.x * CB;

  if (blockIdx.x == 0 && tid == 0) *out = 0.0f;  // zero accumulator for k_pair

  // ---- stage off region: x fixed, y0..y0+2, z 0..48 -> 882 floats ----
  const int x0 = cell0 / 2304;
  const int y0 = (cell0 / 48) % 48;
  for (int e = tid; e < OFFE; e += CB * NW) {
    int r = e / 49, zz = e % 49;       // r = (a*2+dx)*3+dy
    int dy = r % 3, rr = r / 3;
    int dx = rr & 1, a = rr >> 1;
    loff[e] = off[a * 117649 + (x0 + dx) * 2401 + (y0 + dy) * 49 + zz];
  }

  // ---- coalesced topo staging: 64 rows x 24 float4 = 1536 float4, linear ----
  const float4* trow = (const float4*)(topo + (size_t)cell0 * 96);
#pragma unroll
  for (int it = 0; it < 3; ++it) {
    int ch = tid + CB * NW * it;
    float4 v = trow[ch];
    int r  = ch / 24;
    int c4 = (ch % 24) * 4;
    float* dst = &lds[r * PITCH + c4];
    dst[0] = v.x; dst[1] = v.y; dst[2] = v.z; dst[3] = v.w;
  }
  __syncthreads();

  // ---- per-(cell, sixth) compute ----
  const int cell = cell0 + lane;
  const int z = cell % 48;
  const int ly = ((cell / 48) % 48) - y0;        // 0 or 1 (no x-cross mid-block)
  const int lanebase = ly * 49 + z;
  const float* myrow = &lds[lane * PITCH];

  float s = 0.f, mx = 0.f, my = 0.f, mz = 0.f;
  const int wvu = __builtin_amdgcn_readfirstlane(tid >> 6);  // SGPR-uniform
  if (wvu == 0)      do6<0>(loff, lanebase, myrow, s, mx, my, mz);
  else if (wvu == 1) do6<6>(loff, lanebase, myrow, s, mx, my, mz);
  else if (wvu == 2) do6<12>(loff, lanebase, myrow, s, mx, my, mz);
  else if (wvu == 3) do6<18>(loff, lanebase, myrow, s, mx, my, mz);
  else if (wvu == 4) do6<24>(loff, lanebase, myrow, s, mx, my, mz);
  else if (wvu == 5) do6<30>(loff, lanebase, myrow, s, mx, my, mz);
  else if (wvu == 6) do6<36>(loff, lanebase, myrow, s, mx, my, mz);
  else               do6<42>(loff, lanebase, myrow, s, mx, my, mz);

  red[tid] = make_float4(s, mx, my, mz);
  __syncthreads();

  // ---- cross-wave combine: wave 0 sums the 8 eighths, writes float4 ----
  if (tid < 64) {
    float sx = 0.f, sy = 0.f, sz = 0.f, sw = 0.f;
#pragma unroll
    for (int w = 0; w < NW; w++) {
      float4 a = red[lane + 64 * w];
      sx += a.x; sy += a.y; sz += a.z; sw += a.w;
    }
    ws4[cell0 + lane] = make_float4(sx, sy, sz, sw);
  }
}

__global__ __launch_bounds__(256) void k_pair(const float4* __restrict__ ws4,
                                              float* __restrict__ out) {
  int cell = blockIdx.x * 256 + threadIdx.x;
  int z = cell % 48;
  int y = (cell / 48) % 48;
  int x = cell / 2304;
  float4 a = ws4[cell];
  float acc = a.x * a.x - (a.y * a.y + a.z * a.z + a.w * a.w);
  if (z < 47) {
    float4 b = ws4[cell + 1];
    acc += a.x * b.x - (a.y * b.y + a.z * b.z + a.w * b.w);
  }
  if (y < 47) {
    float4 b = ws4[cell + 48];
    acc += a.x * b.x - (a.y * b.y + a.z * b.z + a.w * b.w);
  }
  if (x < 47) {
    float4 b = ws4[cell + 2304];
    acc += a.x * b.x - (a.y * b.y + a.z * b.z + a.w * b.w);
  }
  acc *= 2.0f;
  for (int o = 32; o > 0; o >>= 1) acc += __shfl_down(acc, o, 64);
  __shared__ float lds[4];
  int lane = threadIdx.x & 63;
  int w = threadIdx.x >> 6;
  if (lane == 0) lds[w] = acc;
  __syncthreads();
  if (threadIdx.x == 0) atomicAdd(out, lds[0] + lds[1] + lds[2] + lds[3]);
}

extern "C" void kernel_launch(void* const* d_in, const int* in_sizes, int n_in,
                              void* d_out, int out_size, void* d_ws, size_t ws_size,
                              hipStream_t stream) {
  const float* off  = (const float*)d_in[0];   // [3,49,49,49] f32
  const float* topo = (const float*)d_in[1];   // [110592,96] f32
  float4* ws4 = (float4*)d_ws;                 // 110592 float4 = 1.77 MB
  float* out  = (float*)d_out;                 // scalar f32

  k_cell<<<dim3(NCELLS / CB), dim3(CB * NW), 0, stream>>>(off, topo, ws4, out);
  k_pair<<<dim3(NCELLS / 256), dim3(256), 0, stream>>>(ws4, out);
}